// Round 10
// baseline (384.500 us; speedup 1.0000x reference)
//
#include <hip/hip_runtime.h>
#include <hip/hip_bf16.h>

#define H_DIM 1024
#define I_DIM 2048
#define NE 8
#define NT 4096

typedef __bf16 bf16x8 __attribute__((ext_vector_type(8)));
typedef __bf16 bf16x4 __attribute__((ext_vector_type(4)));
typedef float f32x4 __attribute__((ext_vector_type(4)));

// 16B-chunk index within a [rows][8-chunk] LDS tile, XOR-swizzled (verified
// conflict-free R1-R9: SQ_LDS_BANK_CONFLICT == 0).
__device__ __forceinline__ int swzc(int r, int j) { return r * 8 + (j ^ (r & 7)); }

// async global->LDS, 16B per lane. LDS dest is wave-uniform base (HW adds lane*16).
__device__ __forceinline__ void gl16(const void* g, void* l) {
  __builtin_amdgcn_global_load_lds(
      (const __attribute__((address_space(1))) unsigned int*)g,
      (__attribute__((address_space(3))) unsigned int*)l, 16, 0, 0);
}

__device__ __forceinline__ bf16x8 cvt8(float4 a, float4 b) {
  bf16x8 r;
  r[0] = (__bf16)a.x; r[1] = (__bf16)a.y; r[2] = (__bf16)a.z; r[3] = (__bf16)a.w;
  r[4] = (__bf16)b.x; r[5] = (__bf16)b.y; r[6] = (__bf16)b.z; r[7] = (__bf16)b.w;
  return r;
}

#define NCAST 1728                    // cast blocks; 1728*256*16 == 27*2^18 chunks
#define CSTRIDE (NCAST * 256)         // 442368 threads

// Fused prep. Blocks [0, NCAST): grid-stride weight cast, 16 chunks/thread in
// 4 batches of 4 independent load-pairs (MLP fix for the R9 1.4 TB/s stall).
// Blocks [NCAST, NCAST+1024): router (sigmoid top-2 + lists; fuses x->bf16).
__global__ __launch_bounds__(256) void k_prep(
    const float* __restrict__ wg, const float* __restrict__ wu,
    const float* __restrict__ wd, const float* __restrict__ sg,
    const float* __restrict__ su, const float* __restrict__ sd,
    __bf16* __restrict__ wgb, __bf16* __restrict__ wub, __bf16* __restrict__ wdb,
    __bf16* __restrict__ sgb, __bf16* __restrict__ sub, __bf16* __restrict__ sdb,
    const float* __restrict__ x, const float* __restrict__ rw,
    const float* __restrict__ rbias, __bf16* __restrict__ xb,
    int* __restrict__ counts, int* __restrict__ list,
    int* __restrict__ tE, int* __restrict__ tP, float* __restrict__ tG) {
  if (blockIdx.x < NCAST) {
    const int NW = 1 << 21, NS = 1 << 18;
    int tid0 = blockIdx.x * 256 + threadIdx.x;
#pragma unroll
    for (int o = 0; o < 4; ++o) {
      float4 va[4], vb[4];
      const __bf16* dst[4];
      int off[4];
#pragma unroll
      for (int k = 0; k < 4; ++k) {
        int i = tid0 + (o * 4 + k) * CSTRIDE;   // < 27*2^18 by construction
        const float* s; __bf16* d;
        if (i < 3 * NW) {
          int r = i >> 21; off[k] = i & (NW - 1);
          s = (r == 0) ? wg : (r == 1) ? wu : wd;
          d = (r == 0) ? wgb : (r == 1) ? wub : wdb;
        } else {
          int j = i - 3 * NW;
          int r = j >> 18; off[k] = j & (NS - 1);
          s = (r == 0) ? sg : (r == 1) ? su : sd;
          d = (r == 0) ? sgb : (r == 1) ? sub : sdb;
        }
        const float4* s4 = (const float4*)s;
        va[k] = s4[(size_t)off[k] * 2];
        vb[k] = s4[(size_t)off[k] * 2 + 1];
        dst[k] = d;
      }
#pragma unroll
      for (int k = 0; k < 4; ++k)
        ((bf16x8*)dst[k])[off[k]] = cvt8(va[k], vb[k]);
    }
    return;
  }
  // ---- router ----
  int blk = blockIdx.x - NCAST;               // 0..1023
  int wv = threadIdx.x >> 6, lane = threadIdx.x & 63;
  int t = blk * 4 + wv;
  float acc[NE];
#pragma unroll
  for (int e = 0; e < NE; e++) acc[e] = 0.f;
  const float4* xr = (const float4*)(x + (size_t)t * H_DIM);
  const float4* wr4 = (const float4*)rw;
  bf16x4* xo = (bf16x4*)xb + (size_t)t * (H_DIM / 4);
#pragma unroll
  for (int it = 0; it < 4; ++it) {
    int c = it * 64 + lane;
    float4 xv = xr[c];
    bf16x4 bv;
    bv[0] = (__bf16)xv.x; bv[1] = (__bf16)xv.y;
    bv[2] = (__bf16)xv.z; bv[3] = (__bf16)xv.w;
    xo[c] = bv;
#pragma unroll
    for (int e = 0; e < NE; e++) {
      float4 wv2 = wr4[e * (H_DIM / 4) + c];
      acc[e] += xv.x * wv2.x + xv.y * wv2.y + xv.z * wv2.z + xv.w * wv2.w;
    }
  }
#pragma unroll
  for (int e = 0; e < NE; e++) {
#pragma unroll
    for (int off = 32; off > 0; off >>= 1) acc[e] += __shfl_xor(acc[e], off, 64);
  }
  if (lane == 0) {
    float p[NE];
#pragma unroll
    for (int e = 0; e < NE; e++) p[e] = 1.f / (1.f + expf(-(acc[e] + rbias[e])));
    int e0 = 0;
#pragma unroll
    for (int e = 1; e < NE; e++) if (p[e] > p[e0]) e0 = e;
    int e1 = -1;
#pragma unroll
    for (int e = 0; e < NE; e++) if (e != e0 && (e1 < 0 || p[e] > p[e1])) e1 = e;
    float s = p[e0] + p[e1];
    float g0 = p[e0] / s, g1 = p[e1] / s;
    int p0 = atomicAdd(&counts[e0], 1);
    int p1 = atomicAdd(&counts[e1], 1);
    list[e0 * NT + p0] = t;
    list[e1 * NT + p1] = t;
    tE[t * 2] = e0; tE[t * 2 + 1] = e1;
    tP[t * 2] = p0; tP[t * 2 + 1] = p1;
    tG[t * 2] = g0; tG[t * 2 + 1] = g1;
  }
}

// ---------------------------------------------------------------------------
// Fused gate+up GEMM, m97 config: tile 128 token-rows x 64 i-cols x {g,u}
// (B-tile = 128 rows: b = wc*64 + gu*32 + c -> (gu?u:g) col n0+wc*32+c),
// BK=64, 4 waves (2x2), 64 KB dbuf LDS -> 2 blocks/CU. dim3 grid, n fastest.
// ---------------------------------------------------------------------------
__global__ __launch_bounds__(256, 2) void k_upgate97(
    const __bf16* __restrict__ xb, const __bf16* __restrict__ wgb,
    const __bf16* __restrict__ wub, const __bf16* __restrict__ sgb,
    const __bf16* __restrict__ sub, const int* __restrict__ counts,
    const int* __restrict__ list,
    __bf16* __restrict__ hs, __bf16* __restrict__ hr) {
  int z = blockIdx.z;
  int m0 = blockIdx.y * 128, n0 = blockIdx.x * 64;
  bool sh = (z == NE);
  int count, base = 0;
  const __bf16 *Bg, *Bu;
  if (sh) {
    count = NT; Bg = sgb; Bu = sub;
  } else {
    count = counts[z];
    if (m0 >= count) return;
    for (int e = 0; e < z; e++) base += counts[e];
    Bg = wgb + (size_t)z * (I_DIM * H_DIM);
    Bu = wub + (size_t)z * (I_DIM * H_DIM);
  }

  __shared__ bf16x8 lds[4096];   // [2][A 1024 | B 1024] = 64 KB

  int tid = threadIdx.x, lane = tid & 63, w = tid >> 6;
  int wr = w >> 1, wc = w & 1;
  int fr = lane & 15, fs = lane >> 4;

  const bf16x8* a8 = (const bf16x8*)xb;
  const bf16x8* g8 = (const bf16x8*)Bg;
  const bf16x8* u8 = (const bf16x8*)Bu;

  const bf16x8* pA[4];
  const bf16x8* pB[4];
#pragma unroll
  for (int q = 0; q < 4; q++) {
    int c = q * 256 + tid;                  // chunk 0..1023 (128 rows x 8)
    int r = c >> 3, j = (c & 7) ^ (r & 7);
    int gr = m0 + r;
    int tok = sh ? gr : ((gr < count) ? list[z * NT + gr] : list[z * NT]);
    pA[q] = a8 + (size_t)tok * (H_DIM / 8) + j;
    int G = r >> 6, gu = (r >> 5) & 1, cc = r & 31;
    pB[q] = (gu ? u8 : g8) + (size_t)(n0 + G * 32 + cc) * (H_DIM / 8) + j;
  }

  f32x4 acc[4][4];
#pragma unroll
  for (int m = 0; m < 4; m++)
#pragma unroll
    for (int n = 0; n < 4; n++) acc[m][n] = (f32x4){0.f, 0.f, 0.f, 0.f};

  // prologue: stage tile 0 into buf 0
  {
    bf16x8* dA = lds;
    bf16x8* dB = lds + 1024;
#pragma unroll
    for (int q = 0; q < 4; q++) {
      gl16(pA[q], dA + q * 256 + w * 64);
      gl16(pB[q], dB + q * 256 + w * 64);
    }
  }

  const int NK = H_DIM / 64;  // 16
  for (int kt = 0; kt < NK; ++kt) {
    __syncthreads();           // drains tile kt's loads; WAR-fences buf^1
    if (kt + 1 < NK) {
      bf16x8* dA = lds + ((kt + 1) & 1) * 2048;
      bf16x8* dB = dA + 1024;
      int ko = (kt + 1) * 8;
#pragma unroll
      for (int q = 0; q < 4; q++) {
        gl16(pA[q] + ko, dA + q * 256 + w * 64);
        gl16(pB[q] + ko, dB + q * 256 + w * 64);
      }
    }
    const bf16x8* Ac = lds + (kt & 1) * 2048;
    const bf16x8* Bc = Ac + 1024;
#pragma unroll
    for (int ks = 0; ks < 2; ks++) {
      bf16x8 af[4], bfr[4];
#pragma unroll
      for (int mf = 0; mf < 4; mf++) af[mf] = Ac[swzc(wr * 64 + mf * 16 + fr, ks * 4 + fs)];
#pragma unroll
      for (int nf = 0; nf < 4; nf++) bfr[nf] = Bc[swzc(wc * 64 + nf * 16 + fr, ks * 4 + fs)];
      __builtin_amdgcn_s_setprio(1);
#pragma unroll
      for (int m = 0; m < 4; m++)
#pragma unroll
        for (int n = 0; n < 4; n++)
          acc[m][n] = __builtin_amdgcn_mfma_f32_16x16x32_bf16(af[m], bfr[n], acc[m][n], 0, 0, 0);
      __builtin_amdgcn_s_setprio(0);
    }
  }

  // epilogue: h = silu(g)*u; g = acc[m][np], u = acc[m][np+2]
#pragma unroll
  for (int m = 0; m < 4; m++)
#pragma unroll
    for (int np = 0; np < 2; np++)
#pragma unroll
      for (int q2 = 0; q2 < 4; q2++) {
        int row = wr * 64 + m * 16 + fs * 4 + q2;
        int col = n0 + wc * 32 + np * 16 + fr;
        float g = acc[m][np][q2], u = acc[m][np + 2][q2];
        float h = g * u / (1.f + expf(-g));
        __bf16 hb = (__bf16)h;
        int grow = m0 + row;
        if (sh) hs[(size_t)grow * I_DIM + col] = hb;
        else if (grow < count) hr[(size_t)(base + grow) * I_DIM + col] = hb;
      }
}

// ---------------------------------------------------------------------------
// Down GEMM, m97 config: 128x128 tile, BK=64, 4 waves (2x2), 64 KB dbuf LDS
// -> 2 blocks/CU. dim3 grid (n=8, m=32, z=9), n fastest, NO swizzle.
// ---------------------------------------------------------------------------
__global__ __launch_bounds__(256, 2) void k_down97(
    const __bf16* __restrict__ hs, const __bf16* __restrict__ hr,
    const __bf16* __restrict__ wdb, const __bf16* __restrict__ sdb,
    const int* __restrict__ counts,
    float* __restrict__ out, float* __restrict__ y) {
  int z = blockIdx.z;
  int m0 = blockIdx.y * 128, n0 = blockIdx.x * 128;
  bool sh = (z == NE);
  int count, base = 0;
  const __bf16 *B, *A;
  if (sh) {
    count = NT; B = sdb; A = hs;
  } else {
    count = counts[z];
    if (m0 >= count) return;
    for (int e = 0; e < z; e++) base += counts[e];
    B = wdb + (size_t)z * (H_DIM * I_DIM);
    A = hr + (size_t)base * I_DIM;
  }

  __shared__ bf16x8 lds[4096];   // [2][A 1024 | B 1024] = 64 KB

  int tid = threadIdx.x, lane = tid & 63, w = tid >> 6;
  int wr = w >> 1, wc = w & 1;
  int fr = lane & 15, fs = lane >> 4;

  const bf16x8* a8 = (const bf16x8*)A;
  const bf16x8* b8 = (const bf16x8*)B;

  const bf16x8* pA[4];
  const bf16x8* pB[4];
#pragma unroll
  for (int q = 0; q < 4; q++) {
    int c = q * 256 + tid;                  // chunk 0..1023 (128 rows x 8)
    int r = c >> 3, j = (c & 7) ^ (r & 7);
    int ra = m0 + r; if (ra >= count) ra = count - 1;
    pA[q] = a8 + (size_t)ra * (I_DIM / 8) + j;
    pB[q] = b8 + (size_t)(n0 + r) * (I_DIM / 8) + j;
  }

  f32x4 acc[4][4];
#pragma unroll
  for (int m = 0; m < 4; m++)
#pragma unroll
    for (int n = 0; n < 4; n++) acc[m][n] = (f32x4){0.f, 0.f, 0.f, 0.f};

  // prologue: stage tile 0 into buf 0
  {
    bf16x8* dA = lds;
    bf16x8* dB = lds + 1024;
#pragma unroll
    for (int q = 0; q < 4; q++) {
      gl16(pA[q], dA + q * 256 + w * 64);
      gl16(pB[q], dB + q * 256 + w * 64);
    }
  }

  const int NK = I_DIM / 64;  // 32
  for (int kt = 0; kt < NK; ++kt) {
    __syncthreads();           // drains tile kt's loads; WAR-fences buf^1
    if (kt + 1 < NK) {
      bf16x8* dA = lds + ((kt + 1) & 1) * 2048;
      bf16x8* dB = dA + 1024;
      int ko = (kt + 1) * 8;
#pragma unroll
      for (int q = 0; q < 4; q++) {
        gl16(pA[q] + ko, dA + q * 256 + w * 64);
        gl16(pB[q] + ko, dB + q * 256 + w * 64);
      }
    }
    const bf16x8* Ac = lds + (kt & 1) * 2048;
    const bf16x8* Bc = Ac + 1024;
#pragma unroll
    for (int ks = 0; ks < 2; ks++) {
      bf16x8 af[4], bfr[4];
#pragma unroll
      for (int mf = 0; mf < 4; mf++) af[mf] = Ac[swzc(wr * 64 + mf * 16 + fr, ks * 4 + fs)];
#pragma unroll
      for (int nf = 0; nf < 4; nf++) bfr[nf] = Bc[swzc(wc * 64 + nf * 16 + fr, ks * 4 + fs)];
      __builtin_amdgcn_s_setprio(1);
#pragma unroll
      for (int m = 0; m < 4; m++)
#pragma unroll
        for (int n = 0; n < 4; n++)
          acc[m][n] = __builtin_amdgcn_mfma_f32_16x16x32_bf16(af[m], bfr[n], acc[m][n], 0, 0, 0);
      __builtin_amdgcn_s_setprio(0);
    }
  }

#pragma unroll
  for (int m = 0; m < 4; m++)
#pragma unroll
    for (int n = 0; n < 4; n++)
#pragma unroll
      for (int q2 = 0; q2 < 4; q2++) {
        int row = wr * 64 + m * 16 + fs * 4 + q2;
        int col = n0 + wc * 64 + n * 16 + fr;
        float v = acc[m][n][q2];
        int grow = m0 + row;
        if (sh) out[(size_t)grow * H_DIM + col] = v;
        else if (grow < count) y[(size_t)(base + grow) * H_DIM + col] = v;
      }
}

__global__ __launch_bounds__(256) void k_combine(
    const float* __restrict__ y, const int* __restrict__ counts,
    const int* __restrict__ tE, const int* __restrict__ tP,
    const float* __restrict__ tG, float* __restrict__ out) {
  int t = blockIdx.x;
  int c = threadIdx.x;  // H/4 = 256 float4 per token row
  int bases[NE];
  int s = 0;
#pragma unroll
  for (int e = 0; e < NE; e++) { bases[e] = s; s += counts[e]; }
  int e0 = tE[t * 2], e1 = tE[t * 2 + 1];
  int r0 = bases[e0] + tP[t * 2], r1 = bases[e1] + tP[t * 2 + 1];
  float g0 = tG[t * 2], g1 = tG[t * 2 + 1];
  const float4* y4 = (const float4*)y;
  float4* o4 = (float4*)out;
  float4 sv = o4[(size_t)t * (H_DIM / 4) + c];
  float4 a = y4[(size_t)r0 * (H_DIM / 4) + c];
  float4 b = y4[(size_t)r1 * (H_DIM / 4) + c];
  sv.x += g0 * a.x + g1 * b.x;
  sv.y += g0 * a.y + g1 * b.y;
  sv.z += g0 * a.z + g1 * b.z;
  sv.w += g0 * a.w + g1 * b.w;
  o4[(size_t)t * (H_DIM / 4) + c] = sv;
}

extern "C" void kernel_launch(void* const* d_in, const int* in_sizes, int n_in,
                              void* d_out, int out_size, void* d_ws, size_t ws_size,
                              hipStream_t stream) {
  const float* x = (const float*)d_in[0];
  const float* sg_w = (const float*)d_in[1];
  const float* su_w = (const float*)d_in[2];
  const float* sd_w = (const float*)d_in[3];
  const float* router_w = (const float*)d_in[4];
  const float* routing_bias = (const float*)d_in[5];
  const float* wg = (const float*)d_in[6];
  const float* wu = (const float*)d_in[7];
  const float* wd = (const float*)d_in[8];
  float* out = (float*)d_out;
  char* ws = (char*)d_ws;

  __bf16* xb  = (__bf16*)(ws + 0);            //  8,388,608
  __bf16* hs  = (__bf16*)(ws + 8388608);      // 16,777,216
  __bf16* hr  = (__bf16*)(ws + 25165824);     // 33,554,432
  float*  y   = (float*)(ws + 58720256);      // 33,554,432
  __bf16* wgb = (__bf16*)(ws + 92274688);     // 33,554,432
  __bf16* wub = (__bf16*)(ws + 125829120);    // 33,554,432
  __bf16* wdb = (__bf16*)(ws + 159383552);    // 33,554,432
  __bf16* sgb = (__bf16*)(ws + 192937984);    //  4,194,304
  __bf16* sub = (__bf16*)(ws + 197132288);    //  4,194,304
  __bf16* sdb = (__bf16*)(ws + 201326592);    //  4,194,304
  int* counts = (int*)(ws + 205520896);
  int* list   = (int*)(ws + 205520960);       // 131,072
  int* tE     = (int*)(ws + 205652032);       // 32,768
  int* tP     = (int*)(ws + 205684800);       // 32,768
  float* tG   = (float*)(ws + 205717568);     // 32,768

  hipMemsetAsync(counts, 0, NE * sizeof(int), stream);
  k_prep<<<NCAST + NT / 4, 256, 0, stream>>>(
      wg, wu, wd, sg_w, su_w, sd_w, wgb, wub, wdb, sgb, sub, sdb,
      x, router_w, routing_bias, xb, counts, list, tE, tP, tG);
  dim3 gu(I_DIM / 64, NT / 128, NE + 1);
  k_upgate97<<<gu, 256, 0, stream>>>(xb, wgb, wub, sgb, sub, counts, list, hs, hr);
  dim3 gd(H_DIM / 128, NT / 128, NE + 1);
  k_down97<<<gd, 256, 0, stream>>>(hs, hr, wdb, sdb, counts, out, y);
  k_combine<<<NT, 256, 0, stream>>>(y, counts, tE, tP, tG, out);
}